// Round 3
// baseline (194.083 us; speedup 1.0000x reference)
//
#include <hip/hip_runtime.h>

typedef __bf16 bf16;
typedef __bf16 bf16x8 __attribute__((ext_vector_type(8)));
typedef float  f32x4  __attribute__((ext_vector_type(4)));

#define T_SEQ   2048
#define D_HEAD  64
#define NH      16
#define BH      32
#define C_EMB   1024
#define WS_STRIDE (BH * T_SEQ * D_HEAD)   // 4,194,304 elems per plane
#define XN (4096 * 1024)
#define WN (3072 * 1024)
#define WS_NEEDED ((size_t)(3 * WS_STRIDE + XN + WN) * 2)
#define OUT_F4 1048576                    // out floats / 4

__device__ __forceinline__ bf16x8 cvt8(float4 a, float4 b) {
    bf16x8 r;
    r[0] = (__bf16)a.x; r[1] = (__bf16)a.y; r[2] = (__bf16)a.z; r[3] = (__bf16)a.w;
    r[4] = (__bf16)b.x; r[5] = (__bf16)b.y; r[6] = (__bf16)b.z; r[7] = (__bf16)b.w;
    return r;
}

__device__ __forceinline__ void gl_lds16(const bf16* g, bf16* l) {
    __builtin_amdgcn_global_load_lds(
        (const __attribute__((address_space(1))) unsigned int*)g,
        (__attribute__((address_space(3))) unsigned int*)l,
        16, 0, 0);
}

__device__ __forceinline__ unsigned pack_bf16(float a, float b) {
    union { __bf16 h[2]; unsigned u; } pk;
    pk.h[0] = (__bf16)a; pk.h[1] = (__bf16)b;
    return pk.u;
}

// ---------------------------------------------------------------------------
// Kernel 0: fp32 -> bf16 convert of x and W
// ---------------------------------------------------------------------------
__global__ __launch_bounds__(256) void cvt_bf16(
    const float* __restrict__ x, const float* __restrict__ W,
    bf16* __restrict__ xb, bf16* __restrict__ wb)
{
    const int t = blockIdx.x * 256 + threadIdx.x;
    const float* src; bf16* dst; int base;
    if (t < XN / 8) { src = x; dst = xb; base = t * 8; }
    else           { src = W; dst = wb; base = (t - XN / 8) * 8; }
    float4 a = *(const float4*)(src + base);
    float4 b = *(const float4*)(src + base + 4);
    *(bf16x8*)(dst + base) = cvt8(a, b);
}

// ---------------------------------------------------------------------------
// Kernel 1: qkv = xb @ wb^T + b. BK=64, XOR-swizzled LDS (chunk c at c^(row&7))
// staged via global_load_lds w=16. Also zeroes `out` (grid-stride) and writes
// the V plane transposed: vt[bh][d][t].
// ---------------------------------------------------------------------------
__global__ __launch_bounds__(256) void qkv_gemm2(
    const bf16* __restrict__ xb, const bf16* __restrict__ wb,
    const float* __restrict__ bias, bf16* __restrict__ ws,
    float* __restrict__ out)
{
    __shared__ bf16 As[128 * 64];
    __shared__ bf16 Bs[128 * 64];

    const int tid  = threadIdx.x;
    const int lane = tid & 63;
    const int w    = tid >> 6;
    const int wm   = w >> 1, wn = w & 1;
    const int l15  = lane & 15, l4 = lane >> 4;
    const int bm   = blockIdx.x / 24, bn = blockIdx.x % 24;

    // zero `out` while tiles stream in (replaces the memset dispatch)
    {
        float4 z = {0.f, 0.f, 0.f, 0.f};
        for (int i = blockIdx.x * 256 + tid; i < OUT_F4; i += 768 * 256)
            ((float4*)out)[i] = z;
    }

    // staging: wave w stages A/B rows [w*32, w*32+32), 4 issues each side.
    // lane -> row offset lane>>3, stored chunk lane&7, global chunk swizzled.
    const int srow  = lane >> 3;            // 0..7
    const int csrc  = (lane & 7) ^ srow;    // global chunk to fetch
    const bf16* ag = xb + (size_t)(bm * 128 + w * 32 + srow) * 1024 + csrc * 8;
    const bf16* bg = wb + (size_t)(bn * 128 + w * 32 + srow) * 1024 + csrc * 8;
    bf16* al = &As[w * 2048];
    bf16* bl = &Bs[w * 2048];

    f32x4 acc[4][4];
#pragma unroll
    for (int i = 0; i < 4; i++)
#pragma unroll
        for (int j = 0; j < 4; j++) acc[i][j] = (f32x4){0.f, 0.f, 0.f, 0.f};

    float bv[4];
#pragma unroll
    for (int j = 0; j < 4; j++) bv[j] = bias[bn * 128 + wn * 64 + j * 16 + l15];

    for (int kk = 0; kk < 16; ++kk) {
        __syncthreads();   // prev iteration's fragment reads complete
#pragma unroll
        for (int e = 0; e < 4; e++) {
            gl_lds16(ag + kk * 64 + e * 8 * 1024, al + e * 512);
            gl_lds16(bg + kk * 64 + e * 8 * 1024, bl + e * 512);
        }
        __syncthreads();   // drains vmcnt -> staging visible

        bf16x8 aF[4][2], bF[4][2];
#pragma unroll
        for (int s = 0; s < 4; s++) {
#pragma unroll
            for (int dk = 0; dk < 2; dk++) {
                const int ra = wm * 64 + s * 16 + l15;
                const int rb = wn * 64 + s * 16 + l15;
                aF[s][dk] = *(const bf16x8*)&As[ra * 64 + (((dk * 4 + l4) ^ (ra & 7)) * 8)];
                bF[s][dk] = *(const bf16x8*)&Bs[rb * 64 + (((dk * 4 + l4) ^ (rb & 7)) * 8)];
            }
        }
#pragma unroll
        for (int dk = 0; dk < 2; dk++)
#pragma unroll
            for (int i = 0; i < 4; i++)
#pragma unroll
                for (int j = 0; j < 4; j++)
                    acc[i][j] = __builtin_amdgcn_mfma_f32_16x16x32_bf16(
                        aF[i][dk], bF[j][dk], acc[i][j], 0, 0, 0);
    }

    // epilogue: +bias; q/k planes [bh][t][d]; v plane TRANSPOSED [bh][d][t]
#pragma unroll
    for (int i = 0; i < 4; i++) {
#pragma unroll
        for (int j = 0; j < 4; j++) {
            const int n     = bn * 128 + wn * 64 + j * 16 + l15;
            const int which = n >> 10;
            const int cc    = n & 1023;
            const int h     = cc >> 6, d = cc & 63;
#pragma unroll
            for (int r = 0; r < 4; r++) {
                const int m  = bm * 128 + wm * 64 + i * 16 + l4 * 4 + r;
                const int bi = m >> 11, t = m & 2047;
                const int bh = bi * NH + h;
                const float v = acc[i][j][r] + bv[j];
                size_t idx;
                if (which == 2)
                    idx = 2 * (size_t)WS_STRIDE + ((size_t)bh * D_HEAD + d) * T_SEQ + t;
                else
                    idx = (size_t)which * WS_STRIDE + ((size_t)bh * T_SEQ + t) * D_HEAD + d;
                ws[idx] = (__bf16)v;
            }
        }
    }
}

// ---------------------------------------------------------------------------
// Kernel 1 fallback (ws too small): register-convert GEMM, same epilogue.
// ---------------------------------------------------------------------------
__global__ __launch_bounds__(256) void qkv_gemm(
    const float* __restrict__ x, const float* __restrict__ W,
    const float* __restrict__ bias, bf16* __restrict__ ws,
    float* __restrict__ out)
{
    __shared__ bf16 As[128 * 40];
    __shared__ bf16 Bs[128 * 40];

    const int tid  = threadIdx.x;
    const int lane = tid & 63;
    const int w    = tid >> 6;
    const int wm   = w >> 1, wn = w & 1;
    const int l15  = lane & 15, l4 = lane >> 4;
    const int bm   = blockIdx.x / 24, bn = blockIdx.x % 24;

    {
        float4 z = {0.f, 0.f, 0.f, 0.f};
        for (int i = blockIdx.x * 256 + tid; i < OUT_F4; i += 768 * 256)
            ((float4*)out)[i] = z;
    }

    const int srow = tid >> 1;
    const int scol = (tid & 1) * 16;
    const float* xg = x + (size_t)(bm * 128 + srow) * 1024 + scol;
    const float* wg = W + (size_t)(bn * 128 + srow) * 1024 + scol;
    bf16* asw = &As[srow * 40 + scol];
    bf16* bsw = &Bs[srow * 40 + scol];

    f32x4 acc[4][4];
#pragma unroll
    for (int i = 0; i < 4; i++)
#pragma unroll
        for (int j = 0; j < 4; j++) acc[i][j] = (f32x4){0.f, 0.f, 0.f, 0.f};

    float bv[4];
#pragma unroll
    for (int j = 0; j < 4; j++) bv[j] = bias[bn * 128 + wn * 64 + j * 16 + l15];

    for (int kk = 0; kk < 32; ++kk) {
        const float* xp = xg + kk * 32;
        const float* wp = wg + kk * 32;
        float4 a0 = *(const float4*)(xp + 0);
        float4 a1 = *(const float4*)(xp + 4);
        float4 a2 = *(const float4*)(xp + 8);
        float4 a3 = *(const float4*)(xp + 12);
        float4 b0 = *(const float4*)(wp + 0);
        float4 b1 = *(const float4*)(wp + 4);
        float4 b2 = *(const float4*)(wp + 8);
        float4 b3 = *(const float4*)(wp + 12);

        __syncthreads();
        *(bf16x8*)(asw + 0) = cvt8(a0, a1);
        *(bf16x8*)(asw + 8) = cvt8(a2, a3);
        *(bf16x8*)(bsw + 0) = cvt8(b0, b1);
        *(bf16x8*)(bsw + 8) = cvt8(b2, b3);
        __syncthreads();

        bf16x8 aF[4], bF[4];
#pragma unroll
        for (int s = 0; s < 4; s++) {
            aF[s] = *(const bf16x8*)&As[(wm * 64 + s * 16 + l15) * 40 + l4 * 8];
            bF[s] = *(const bf16x8*)&Bs[(wn * 64 + s * 16 + l15) * 40 + l4 * 8];
        }
#pragma unroll
        for (int i = 0; i < 4; i++)
#pragma unroll
            for (int j = 0; j < 4; j++)
                acc[i][j] = __builtin_amdgcn_mfma_f32_16x16x32_bf16(
                    aF[i], bF[j], acc[i][j], 0, 0, 0);
    }

#pragma unroll
    for (int i = 0; i < 4; i++) {
#pragma unroll
        for (int j = 0; j < 4; j++) {
            const int n     = bn * 128 + wn * 64 + j * 16 + l15;
            const int which = n >> 10;
            const int cc    = n & 1023;
            const int h     = cc >> 6, d = cc & 63;
#pragma unroll
            for (int r = 0; r < 4; r++) {
                const int m  = bm * 128 + wm * 64 + i * 16 + l4 * 4 + r;
                const int bi = m >> 11, t = m & 2047;
                const int bh = bi * NH + h;
                const float v = acc[i][j][r] + bv[j];
                size_t idx;
                if (which == 2)
                    idx = 2 * (size_t)WS_STRIDE + ((size_t)bh * D_HEAD + d) * T_SEQ + t;
                else
                    idx = (size_t)which * WS_STRIDE + ((size_t)bh * T_SEQ + t) * D_HEAD + d;
                ws[idx] = (__bf16)v;
            }
        }
    }
}

// ---------------------------------------------------------------------------
// Kernel 2: causal ReLU attention. S^T = MFMA(K,Q); P transposed back to
// A-layout via ds_bpermute (no P LDS round-trip). K and V^T staged via
// global_load_lds into XOR-swizzled LDS. Key range split into 4 chunks per
// (bh,qt) -> 2048 blocks; O combined via fp32 atomicAdd (out pre-zeroed).
// ---------------------------------------------------------------------------
__global__ __launch_bounds__(256) void attn(
    const bf16* __restrict__ ws, float* __restrict__ out)
{
    __shared__ bf16 Ks[64 * 64];     // [key][d], chunk-swizzled
    __shared__ bf16 Vts[64 * 64];    // [d][key], chunk-swizzled

    const int tid  = threadIdx.x;
    const int lane = tid & 63;
    const int w    = tid >> 6;
    const int l15  = lane & 15, qd = lane >> 4;

    // XCD swizzle: 4 sibling chunks of one (bh,qt) share an XCD (blockIdx%8)
    const int x  = blockIdx.x & 7, m = blockIdx.x >> 3;
    const int c  = m & 3;
    const int p  = x * 64 + (m >> 2);     // 0..511
    const int bh = p & 31, qt = p >> 5;

    const int Tq  = 2 * qt + 2;
    const int jt0 = (c * Tq) >> 2;
    const int jt1 = (((c + 1) * Tq) >> 2) - 1;
    if (jt0 > jt1) return;                // block-uniform; before any barrier

    const bf16* qg = ws + (size_t)bh * (T_SEQ * D_HEAD);
    const bf16* kg = ws + WS_STRIDE + (size_t)bh * (T_SEQ * D_HEAD);
    const bf16* vt = ws + 2 * (size_t)WS_STRIDE + (size_t)bh * (D_HEAD * T_SEQ);
    const int qbase = qt * 128;

    // Q fragments direct global->regs, live across whole loop
    bf16x8 qF[2][2];
#pragma unroll
    for (int sm = 0; sm < 2; sm++)
#pragma unroll
        for (int dk = 0; dk < 2; dk++)
            qF[sm][dk] = *(const bf16x8*)(qg + (qbase + w * 32 + sm * 16 + l15) * 64
                                          + dk * 32 + qd * 8);

    f32x4 o[2][4];
#pragma unroll
    for (int sm = 0; sm < 2; sm++)
#pragma unroll
        for (int sd = 0; sd < 4; sd++) o[sm][sd] = (f32x4){0.f, 0.f, 0.f, 0.f};

    // staging lane mapping (shared by K and Vt)
    const int srow = lane >> 3;           // 0..7
    const int csrc = (lane & 7) ^ srow;   // swizzled global chunk
    const bf16* kgs = kg + (w * 16 + srow) * 64 + csrc * 8;
    const bf16* vgs = vt + (size_t)(w * 16 + srow) * T_SEQ + csrc * 8;

    // bpermute source addresses (bytes): quad (qd&1)*2 + h, same column l15
    const int addrA = (l15 | (((qd & 1) * 2) << 4)) * 4;
    const int addrB = addrA + 64;
    const bool loQuad = (qd < 2);
    const float scale = 0.125f;           // 1/sqrt(64)

    for (int jt = jt0; jt <= jt1; ++jt) {
        __syncthreads();   // prev iteration's LDS reads complete
#pragma unroll
        for (int e = 0; e < 2; e++) {
            gl_lds16(kgs + (size_t)(jt * 64 + e * 8) * 64, &Ks[w * 1024 + e * 512]);
            gl_lds16(vgs + jt * 64 + (size_t)(e * 8) * T_SEQ, &Vts[w * 1024 + e * 512]);
        }
        __syncthreads();   // drains vmcnt -> staging visible

        // ---- S^T = K Q^T : lane holds key=jt*64+kn*16+qd*4+r, q=qbase+w*32+sm*16+l15
        f32x4 sT[4][2];
#pragma unroll
        for (int kn = 0; kn < 4; kn++)
#pragma unroll
            for (int sm = 0; sm < 2; sm++) sT[kn][sm] = (f32x4){0.f, 0.f, 0.f, 0.f};
#pragma unroll
        for (int kn = 0; kn < 4; kn++) {
#pragma unroll
            for (int dk = 0; dk < 2; dk++) {
                const int row = kn * 16 + l15;
                bf16x8 kF = *(const bf16x8*)&Ks[row * 64 + (((dk * 4 + qd) ^ (row & 7)) * 8)];
#pragma unroll
                for (int sm = 0; sm < 2; sm++)
                    sT[kn][sm] = __builtin_amdgcn_mfma_f32_16x16x32_bf16(
                        kF, qF[sm][dk], sT[kn][sm], 0, 0, 0);
            }
        }

        // ---- scale + relu + causal mask + pack to bf16 dwords ----
        const bool need_mask = (jt >= 2 * qt);
        unsigned PK[2][4][2];             // [sm][kn][p]: p0=regs{0,1}, p1=regs{2,3}
#pragma unroll
        for (int sm = 0; sm < 2; sm++) {
            const int q = qbase + w * 32 + sm * 16 + l15;
#pragma unroll
            for (int kn = 0; kn < 4; kn++) {
                float v[4];
#pragma unroll
                for (int r = 0; r < 4; r++) {
                    const int key = jt * 64 + kn * 16 + qd * 4 + r;
                    float val = fmaxf(sT[kn][sm][r] * scale, 0.f);
                    if (need_mask && q < key) val = 0.f;
                    v[r] = val;
                }
                PK[sm][kn][0] = pack_bf16(v[0], v[1]);
                PK[sm][kn][1] = pack_bf16(v[2], v[3]);
            }
        }

        // ---- transpose P to A-layout via ds_bpermute; O += P V ----
#pragma unroll
        for (int kk = 0; kk < 2; kk++) {
            bf16x8 pF[2];
#pragma unroll
            for (int sm = 0; sm < 2; sm++) {
                union { unsigned dw[4]; bf16x8 v; } u;
#pragma unroll
                for (int d = 0; d < 4; d++) {
                    const int pp   = d & 1;
                    const int addr = (d >> 1) ? addrB : addrA;
                    int lo = __builtin_amdgcn_ds_bpermute(addr, (int)PK[sm][2 * kk + 0][pp]);
                    int hi = __builtin_amdgcn_ds_bpermute(addr, (int)PK[sm][2 * kk + 1][pp]);
                    u.dw[d] = loQuad ? (unsigned)lo : (unsigned)hi;
                }
                pF[sm] = u.v;
            }
#pragma unroll
            for (int sd = 0; sd < 4; sd++) {
                const int row = sd * 16 + l15;
                bf16x8 vF = *(const bf16x8*)&Vts[row * 64 + (((kk * 4 + qd) ^ (row & 7)) * 8)];
#pragma unroll
                for (int sm = 0; sm < 2; sm++)
                    o[sm][sd] = __builtin_amdgcn_mfma_f32_16x16x32_bf16(
                        pF[sm], vF, o[sm][sd], 0, 0, 0);
            }
        }
    }

    // ---- epilogue: atomic-accumulate O into out[b][t][h*64+d] ----
    const int b = bh >> 4, h = bh & 15;
#pragma unroll
    for (int sm = 0; sm < 2; sm++) {
#pragma unroll
        for (int sd = 0; sd < 4; sd++) {
            const int d = sd * 16 + l15;
#pragma unroll
            for (int r = 0; r < 4; r++) {
                const int t = qbase + w * 32 + sm * 16 + qd * 4 + r;
                unsafeAtomicAdd(&out[((size_t)b * T_SEQ + t) * C_EMB + h * 64 + d],
                                o[sm][sd][r]);
            }
        }
    }
}

extern "C" void kernel_launch(void* const* d_in, const int* in_sizes, int n_in,
                              void* d_out, int out_size, void* d_ws, size_t ws_size,
                              hipStream_t stream) {
    const float* x    = (const float*)d_in[0];
    const float* W    = (const float*)d_in[1];
    const float* bias = (const float*)d_in[2];
    float* out        = (float*)d_out;
    bf16*  ws         = (bf16*)d_ws;

    if (ws_size >= WS_NEEDED) {
        bf16* xb = ws + 3 * (size_t)WS_STRIDE;
        bf16* wb = xb + XN;
        cvt_bf16<<<dim3(3584), dim3(256), 0, stream>>>(x, W, xb, wb);
        qkv_gemm2<<<dim3(768), dim3(256), 0, stream>>>(xb, wb, bias, ws, out);
    } else {
        qkv_gemm<<<dim3(768), dim3(256), 0, stream>>>(x, W, bias, ws, out);
    }
    attn<<<dim3(2048), dim3(256), 0, stream>>>(ws, out);
}

// Round 4
// 192.279 us; speedup vs baseline: 1.0094x; 1.0094x over previous
//
#include <hip/hip_runtime.h>

typedef __bf16 bf16;
typedef __bf16 bf16x8 __attribute__((ext_vector_type(8)));
typedef float  f32x4  __attribute__((ext_vector_type(4)));

#define T_SEQ   2048
#define D_HEAD  64
#define NH      16
#define BH      32
#define C_EMB   1024
#define WS_STRIDE (BH * T_SEQ * D_HEAD)   // 4,194,304 elems per plane
#define XN (4096 * 1024)
#define WN (3072 * 1024)
#define WS_NEEDED ((size_t)(3 * WS_STRIDE + XN + WN) * 2)
#define OUT_F4 1048576                    // out floats / 4

__device__ __forceinline__ bf16x8 cvt8(float4 a, float4 b) {
    bf16x8 r;
    r[0] = (__bf16)a.x; r[1] = (__bf16)a.y; r[2] = (__bf16)a.z; r[3] = (__bf16)a.w;
    r[4] = (__bf16)b.x; r[5] = (__bf16)b.y; r[6] = (__bf16)b.z; r[7] = (__bf16)b.w;
    return r;
}

__device__ __forceinline__ void gl_lds16(const bf16* g, bf16* l) {
    __builtin_amdgcn_global_load_lds(
        (const __attribute__((address_space(1))) unsigned int*)g,
        (__attribute__((address_space(3))) unsigned int*)l,
        16, 0, 0);
}

__device__ __forceinline__ unsigned pack_bf16(float a, float b) {
    union { __bf16 h[2]; unsigned u; } pk;
    pk.h[0] = (__bf16)a; pk.h[1] = (__bf16)b;
    return pk.u;
}

// ---------------------------------------------------------------------------
// Kernel 0: fp32 -> bf16 convert of x and W
// ---------------------------------------------------------------------------
__global__ __launch_bounds__(256) void cvt_bf16(
    const float* __restrict__ x, const float* __restrict__ W,
    bf16* __restrict__ xb, bf16* __restrict__ wb)
{
    const int t = blockIdx.x * 256 + threadIdx.x;
    const float* src; bf16* dst; int base;
    if (t < XN / 8) { src = x; dst = xb; base = t * 8; }
    else           { src = W; dst = wb; base = (t - XN / 8) * 8; }
    float4 a = *(const float4*)(src + base);
    float4 b = *(const float4*)(src + base + 4);
    *(bf16x8*)(dst + base) = cvt8(a, b);
}

// ---------------------------------------------------------------------------
// Kernel 1: qkv = xb @ wb^T + b. BK=64, XOR-swizzled LDS (chunk c at c^(row&7))
// staged via global_load_lds w=16. Also zeroes `out` (grid-stride) and writes
// the V plane transposed: vt[bh][d][t].
// ---------------------------------------------------------------------------
__global__ __launch_bounds__(256) void qkv_gemm2(
    const bf16* __restrict__ xb, const bf16* __restrict__ wb,
    const float* __restrict__ bias, bf16* __restrict__ ws,
    float* __restrict__ out)
{
    __shared__ bf16 As[128 * 64];
    __shared__ bf16 Bs[128 * 64];

    const int tid  = threadIdx.x;
    const int lane = tid & 63;
    const int w    = tid >> 6;
    const int wm   = w >> 1, wn = w & 1;
    const int l15  = lane & 15, l4 = lane >> 4;
    const int bm   = blockIdx.x / 24, bn = blockIdx.x % 24;

    // zero `out` while tiles stream in (replaces the memset dispatch)
    {
        float4 z = {0.f, 0.f, 0.f, 0.f};
        for (int i = blockIdx.x * 256 + tid; i < OUT_F4; i += 768 * 256)
            ((float4*)out)[i] = z;
    }

    const int srow  = lane >> 3;            // 0..7
    const int csrc  = (lane & 7) ^ srow;    // global chunk to fetch (XOR swizzle)
    const bf16* ag = xb + (size_t)(bm * 128 + w * 32 + srow) * 1024 + csrc * 8;
    const bf16* bg = wb + (size_t)(bn * 128 + w * 32 + srow) * 1024 + csrc * 8;
    bf16* al = &As[w * 2048];
    bf16* bl = &Bs[w * 2048];

    f32x4 acc[4][4];
#pragma unroll
    for (int i = 0; i < 4; i++)
#pragma unroll
        for (int j = 0; j < 4; j++) acc[i][j] = (f32x4){0.f, 0.f, 0.f, 0.f};

    float bv[4];
#pragma unroll
    for (int j = 0; j < 4; j++) bv[j] = bias[bn * 128 + wn * 64 + j * 16 + l15];

    for (int kk = 0; kk < 16; ++kk) {
        __syncthreads();   // prev iteration's fragment reads complete
#pragma unroll
        for (int e = 0; e < 4; e++) {
            gl_lds16(ag + kk * 64 + e * 8 * 1024, al + e * 512);
            gl_lds16(bg + kk * 64 + e * 8 * 1024, bl + e * 512);
        }
        __syncthreads();   // drains vmcnt -> staging visible

        bf16x8 aF[4][2], bF[4][2];
#pragma unroll
        for (int s = 0; s < 4; s++) {
#pragma unroll
            for (int dk = 0; dk < 2; dk++) {
                const int ra = wm * 64 + s * 16 + l15;
                const int rb = wn * 64 + s * 16 + l15;
                aF[s][dk] = *(const bf16x8*)&As[ra * 64 + (((dk * 4 + l4) ^ (ra & 7)) * 8)];
                bF[s][dk] = *(const bf16x8*)&Bs[rb * 64 + (((dk * 4 + l4) ^ (rb & 7)) * 8)];
            }
        }
#pragma unroll
        for (int dk = 0; dk < 2; dk++)
#pragma unroll
            for (int i = 0; i < 4; i++)
#pragma unroll
                for (int j = 0; j < 4; j++)
                    acc[i][j] = __builtin_amdgcn_mfma_f32_16x16x32_bf16(
                        aF[i][dk], bF[j][dk], acc[i][j], 0, 0, 0);
    }

    // epilogue: +bias; q/k planes [bh][t][d]; v plane TRANSPOSED [bh][d][t]
#pragma unroll
    for (int i = 0; i < 4; i++) {
#pragma unroll
        for (int j = 0; j < 4; j++) {
            const int n     = bn * 128 + wn * 64 + j * 16 + l15;
            const int which = n >> 10;
            const int cc    = n & 1023;
            const int h     = cc >> 6, d = cc & 63;
#pragma unroll
            for (int r = 0; r < 4; r++) {
                const int m  = bm * 128 + wm * 64 + i * 16 + l4 * 4 + r;
                const int bi = m >> 11, t = m & 2047;
                const int bh = bi * NH + h;
                const float v = acc[i][j][r] + bv[j];
                size_t idx;
                if (which == 2)
                    idx = 2 * (size_t)WS_STRIDE + ((size_t)bh * D_HEAD + d) * T_SEQ + t;
                else
                    idx = (size_t)which * WS_STRIDE + ((size_t)bh * T_SEQ + t) * D_HEAD + d;
                ws[idx] = (__bf16)v;
            }
        }
    }
}

// ---------------------------------------------------------------------------
// Kernel 1 fallback (ws too small): register-convert GEMM, same epilogue.
// ---------------------------------------------------------------------------
__global__ __launch_bounds__(256) void qkv_gemm(
    const float* __restrict__ x, const float* __restrict__ W,
    const float* __restrict__ bias, bf16* __restrict__ ws,
    float* __restrict__ out)
{
    __shared__ bf16 As[128 * 40];
    __shared__ bf16 Bs[128 * 40];

    const int tid  = threadIdx.x;
    const int lane = tid & 63;
    const int w    = tid >> 6;
    const int wm   = w >> 1, wn = w & 1;
    const int l15  = lane & 15, l4 = lane >> 4;
    const int bm   = blockIdx.x / 24, bn = blockIdx.x % 24;

    {
        float4 z = {0.f, 0.f, 0.f, 0.f};
        for (int i = blockIdx.x * 256 + tid; i < OUT_F4; i += 768 * 256)
            ((float4*)out)[i] = z;
    }

    const int srow = tid >> 1;
    const int scol = (tid & 1) * 16;
    const float* xg = x + (size_t)(bm * 128 + srow) * 1024 + scol;
    const float* wg = W + (size_t)(bn * 128 + srow) * 1024 + scol;
    bf16* asw = &As[srow * 40 + scol];
    bf16* bsw = &Bs[srow * 40 + scol];

    f32x4 acc[4][4];
#pragma unroll
    for (int i = 0; i < 4; i++)
#pragma unroll
        for (int j = 0; j < 4; j++) acc[i][j] = (f32x4){0.f, 0.f, 0.f, 0.f};

    float bv[4];
#pragma unroll
    for (int j = 0; j < 4; j++) bv[j] = bias[bn * 128 + wn * 64 + j * 16 + l15];

    for (int kk = 0; kk < 32; ++kk) {
        const float* xp = xg + kk * 32;
        const float* wp = wg + kk * 32;
        float4 a0 = *(const float4*)(xp + 0);
        float4 a1 = *(const float4*)(xp + 4);
        float4 a2 = *(const float4*)(xp + 8);
        float4 a3 = *(const float4*)(xp + 12);
        float4 b0 = *(const float4*)(wp + 0);
        float4 b1 = *(const float4*)(wp + 4);
        float4 b2 = *(const float4*)(wp + 8);
        float4 b3 = *(const float4*)(wp + 12);

        __syncthreads();
        *(bf16x8*)(asw + 0) = cvt8(a0, a1);
        *(bf16x8*)(asw + 8) = cvt8(a2, a3);
        *(bf16x8*)(bsw + 0) = cvt8(b0, b1);
        *(bf16x8*)(bsw + 8) = cvt8(b2, b3);
        __syncthreads();

        bf16x8 aF[4], bF[4];
#pragma unroll
        for (int s = 0; s < 4; s++) {
            aF[s] = *(const bf16x8*)&As[(wm * 64 + s * 16 + l15) * 40 + l4 * 8];
            bF[s] = *(const bf16x8*)&Bs[(wn * 64 + s * 16 + l15) * 40 + l4 * 8];
        }
#pragma unroll
        for (int i = 0; i < 4; i++)
#pragma unroll
            for (int j = 0; j < 4; j++)
                acc[i][j] = __builtin_amdgcn_mfma_f32_16x16x32_bf16(
                    aF[i], bF[j], acc[i][j], 0, 0, 0);
    }

#pragma unroll
    for (int i = 0; i < 4; i++) {
#pragma unroll
        for (int j = 0; j < 4; j++) {
            const int n     = bn * 128 + wn * 64 + j * 16 + l15;
            const int which = n >> 10;
            const int cc    = n & 1023;
            const int h     = cc >> 6, d = cc & 63;
#pragma unroll
            for (int r = 0; r < 4; r++) {
                const int m  = bm * 128 + wm * 64 + i * 16 + l4 * 4 + r;
                const int bi = m >> 11, t = m & 2047;
                const int bh = bi * NH + h;
                const float v = acc[i][j][r] + bv[j];
                size_t idx;
                if (which == 2)
                    idx = 2 * (size_t)WS_STRIDE + ((size_t)bh * D_HEAD + d) * T_SEQ + t;
                else
                    idx = (size_t)which * WS_STRIDE + ((size_t)bh * T_SEQ + t) * D_HEAD + d;
                ws[idx] = (__bf16)v;
            }
        }
    }
}

// ---------------------------------------------------------------------------
// Kernel 2: causal ReLU attention — NO LDS, NO BARRIERS.
// All K/V fragments loaded direct global->VGPR (full-cacheline patterns);
// S^T = MFMA(K,Q); P transposed to A-layout via ds_bpermute; O += P·V.
// Round-2 block mapping (bh = blk&31 -> 4 bh planes per XCD L2), 2-way
// key-range split; O combined via fp32 atomicAdd into pre-zeroed out.
// ---------------------------------------------------------------------------
__global__ __launch_bounds__(256) void attn(
    const bf16* __restrict__ ws, float* __restrict__ out)
{
    const int tid  = threadIdx.x;
    const int lane = tid & 63;
    const int w    = tid >> 6;
    const int l15  = lane & 15, qd = lane >> 4;

    const int bh   = blockIdx.x & 31;      // XCD = blk&7 -> bh mod 8 affinity
    const int rest = blockIdx.x >> 5;      // 0..31
    const int qt   = rest >> 1;            // 0..15
    const int half = rest & 1;

    const bf16* qg = ws + (size_t)bh * (T_SEQ * D_HEAD);
    const bf16* kg = ws + WS_STRIDE + (size_t)bh * (T_SEQ * D_HEAD);
    const bf16* vt = ws + 2 * (size_t)WS_STRIDE + (size_t)bh * (D_HEAD * T_SEQ);
    const int qbase = qt * 128;

    // Q fragments: this wave's 32 q-rows, live across whole loop
    bf16x8 qF[2][2];
#pragma unroll
    for (int sm = 0; sm < 2; sm++)
#pragma unroll
        for (int dk = 0; dk < 2; dk++)
            qF[sm][dk] = *(const bf16x8*)(qg + (qbase + w * 32 + sm * 16 + l15) * 64
                                          + dk * 32 + qd * 8);

    f32x4 o[2][4];
#pragma unroll
    for (int sm = 0; sm < 2; sm++)
#pragma unroll
        for (int sd = 0; sd < 4; sd++) o[sm][sd] = (f32x4){0.f, 0.f, 0.f, 0.f};

    // bpermute source addresses (bytes): quad (qd&1)*2 + h, same column l15
    const int addrA = (l15 | (((qd & 1) * 2) << 4)) * 4;
    const int addrB = addrA + 64;
    const bool loQuad = (qd < 2);
    const float scale = 0.125f;           // 1/sqrt(64)

    const int jt0 = half * (qt + 1);
    const int jt1 = jt0 + qt;
    for (int jt = jt0; jt <= jt1; ++jt) {
        // ---- K fragments direct: A[m=key][k=d]; 16 rows x 32 cols / instr ----
        bf16x8 kF[4][2];
#pragma unroll
        for (int kn = 0; kn < 4; kn++)
#pragma unroll
            for (int dk = 0; dk < 2; dk++)
                kF[kn][dk] = *(const bf16x8*)(kg + (size_t)(jt * 64 + kn * 16 + l15) * 64
                                              + dk * 32 + qd * 8);
        // ---- V fragments direct from transposed plane: B[k=key][n=d] ----
        bf16x8 vF[4][2];
#pragma unroll
        for (int sd = 0; sd < 4; sd++)
#pragma unroll
            for (int kk = 0; kk < 2; kk++)
                vF[sd][kk] = *(const bf16x8*)(vt + (size_t)(sd * 16 + l15) * T_SEQ
                                              + jt * 64 + kk * 32 + qd * 8);

        // ---- S^T = K Q^T : lane holds key=kn*16+qd*4+r (rows), q=w*32+sm*16+l15
        f32x4 sT[4][2];
#pragma unroll
        for (int kn = 0; kn < 4; kn++)
#pragma unroll
            for (int sm = 0; sm < 2; sm++) sT[kn][sm] = (f32x4){0.f, 0.f, 0.f, 0.f};
#pragma unroll
        for (int kn = 0; kn < 4; kn++)
#pragma unroll
            for (int dk = 0; dk < 2; dk++)
#pragma unroll
                for (int sm = 0; sm < 2; sm++)
                    sT[kn][sm] = __builtin_amdgcn_mfma_f32_16x16x32_bf16(
                        kF[kn][dk], qF[sm][dk], sT[kn][sm], 0, 0, 0);

        // ---- scale + relu + causal mask + pack to bf16 dwords ----
        const bool need_mask = (jt >= 2 * qt);
        unsigned PK[2][4][2];             // [sm][kn][p]: p0=regs{0,1}, p1=regs{2,3}
#pragma unroll
        for (int sm = 0; sm < 2; sm++) {
            const int q = qbase + w * 32 + sm * 16 + l15;
#pragma unroll
            for (int kn = 0; kn < 4; kn++) {
                float v[4];
#pragma unroll
                for (int r = 0; r < 4; r++) {
                    const int key = jt * 64 + kn * 16 + qd * 4 + r;
                    float val = fmaxf(sT[kn][sm][r] * scale, 0.f);
                    if (need_mask && q < key) val = 0.f;
                    v[r] = val;
                }
                PK[sm][kn][0] = pack_bf16(v[0], v[1]);
                PK[sm][kn][1] = pack_bf16(v[2], v[3]);
            }
        }

        // ---- transpose P to A-layout via ds_bpermute; O += P V ----
#pragma unroll
        for (int kk = 0; kk < 2; kk++) {
            bf16x8 pF[2];
#pragma unroll
            for (int sm = 0; sm < 2; sm++) {
                union { unsigned dw[4]; bf16x8 v; } u;
#pragma unroll
                for (int d = 0; d < 4; d++) {
                    const int pp   = d & 1;
                    const int addr = (d >> 1) ? addrB : addrA;
                    int lo = __builtin_amdgcn_ds_bpermute(addr, (int)PK[sm][2 * kk + 0][pp]);
                    int hi = __builtin_amdgcn_ds_bpermute(addr, (int)PK[sm][2 * kk + 1][pp]);
                    u.dw[d] = loQuad ? (unsigned)lo : (unsigned)hi;
                }
                pF[sm] = u.v;
            }
#pragma unroll
            for (int sd = 0; sd < 4; sd++)
#pragma unroll
                for (int sm = 0; sm < 2; sm++)
                    o[sm][sd] = __builtin_amdgcn_mfma_f32_16x16x32_bf16(
                        pF[sm], vF[sd][kk], o[sm][sd], 0, 0, 0);
        }
    }

    // ---- epilogue: atomic-accumulate O into out[b][t][h*64+d] ----
    const int b = bh >> 4, h = bh & 15;
#pragma unroll
    for (int sm = 0; sm < 2; sm++) {
#pragma unroll
        for (int sd = 0; sd < 4; sd++) {
            const int d = sd * 16 + l15;
#pragma unroll
            for (int r = 0; r < 4; r++) {
                const int t = qbase + w * 32 + sm * 16 + qd * 4 + r;
                unsafeAtomicAdd(&out[((size_t)b * T_SEQ + t) * C_EMB + h * 64 + d],
                                o[sm][sd][r]);
            }
        }
    }
}

extern "C" void kernel_launch(void* const* d_in, const int* in_sizes, int n_in,
                              void* d_out, int out_size, void* d_ws, size_t ws_size,
                              hipStream_t stream) {
    const float* x    = (const float*)d_in[0];
    const float* W    = (const float*)d_in[1];
    const float* bias = (const float*)d_in[2];
    float* out        = (float*)d_out;
    bf16*  ws         = (bf16*)d_ws;

    if (ws_size >= WS_NEEDED) {
        bf16* xb = ws + 3 * (size_t)WS_STRIDE;
        bf16* wb = xb + XN;
        cvt_bf16<<<dim3(3584), dim3(256), 0, stream>>>(x, W, xb, wb);
        qkv_gemm2<<<dim3(768), dim3(256), 0, stream>>>(xb, wb, bias, ws, out);
    } else {
        qkv_gemm<<<dim3(768), dim3(256), 0, stream>>>(x, W, bias, ws, out);
    }
    attn<<<dim3(1024), dim3(256), 0, stream>>>(ws, out);
}